// Round 2
// baseline (9365.723 us; speedup 1.0000x reference)
//
#include <hip/hip_runtime.h>
#include <math.h>

#define NEGV (-100000.0f)
constexpr int Bn = 64, Sn = 512, En = 256, Hn = 256, HIDn = 512, Tn = 9;
constexpr int START_T = Tn - 2, STOP_T = Tn - 1;
constexpr int Mn = Bn * Sn; // 32768 rows

typedef unsigned int u32;
typedef unsigned short u16;
typedef unsigned long long u64;
typedef short short8 __attribute__((ext_vector_type(8)));
typedef float f32x4 __attribute__((ext_vector_type(4)));

__device__ __forceinline__ float sigf(float x) { return 1.0f / (1.0f + __expf(-x)); }
__device__ __forceinline__ float tanh_f(float x) { return 2.0f / (1.0f + __expf(-2.0f * x)) - 1.0f; }
__device__ __forceinline__ u16 f2bf(float f) {
  u32 u = __float_as_uint(f);
  return (u16)((u + 0x7fffu + ((u >> 16) & 1u)) >> 16);
}
__device__ __forceinline__ float bflo(u32 u) { return __uint_as_float(u << 16); }
__device__ __forceinline__ float bfhi(u32 u) { return __uint_as_float(u & 0xffff0000u); }
__device__ __forceinline__ float b2f(u16 v) { return __uint_as_float((u32)v << 16); }

// ---------------- prep: all weights to bf16 MFMA B-fragment order ----------------
// whh frags (recur v7): wfragR[d][w][g][ks][lane][j]; wave w owns units w*16+(lane&15);
//                       row=g*256 + w*16 + (lane&15); k=ks*32+((lane>>4)&3)*8+j
// wih frags (gemm):     wifrag[d][nb][w][ks][lane][j]; n=nb*64+w*16+(lane&15); k=ks*32+((lane>>4)&3)*8+j
__global__ void prep_kernel(const float* __restrict__ wih0, const float* __restrict__ whh0,
                            const float* __restrict__ bih0, const float* __restrict__ bhh0,
                            const float* __restrict__ wih1, const float* __restrict__ whh1,
                            const float* __restrict__ bih1, const float* __restrict__ bhh1,
                            u16* __restrict__ wifrag0, u16* __restrict__ wifrag1,
                            u16* __restrict__ wfrag0, u16* __restrict__ wfrag1,
                            float* __restrict__ bias0, float* __restrict__ bias1) {
  int tid = blockIdx.x * blockDim.x + threadIdx.x;
  int nth = gridDim.x * blockDim.x;
  // wih0 frags: K=256, KS=8 -> 2*16*4*8*64*8 = 524288 u16
  for (int idx = tid; idx < 524288; idx += nth) {
    int j = idx & 7, lane = (idx >> 3) & 63, ks = (idx >> 9) & 7,
        w2 = (idx >> 12) & 3, nb = (idx >> 14) & 15, d = (idx >> 18) & 1;
    int n = nb * 64 + w2 * 16 + (lane & 15);
    int k = ks * 32 + ((lane >> 4) & 3) * 8 + j;
    wifrag0[idx] = f2bf(wih0[(d * 1024 + n) * 256 + k]);
  }
  // wih1 frags: K=512, KS=16 -> 2*16*4*16*64*8 = 1048576 u16
  for (int idx = tid; idx < 1048576; idx += nth) {
    int j = idx & 7, lane = (idx >> 3) & 63, ks = (idx >> 9) & 15,
        w2 = (idx >> 13) & 3, nb = (idx >> 15) & 15, d = (idx >> 19) & 1;
    int n = nb * 64 + w2 * 16 + (lane & 15);
    int k = ks * 32 + ((lane >> 4) & 3) * 8 + j;
    wifrag1[idx] = f2bf(wih1[(d * 1024 + n) * 512 + k]);
  }
  // whh frags, v7 layout: [d][w][g][ks][lane][j]
  for (int idx = tid; idx < 524288; idx += nth) {
    int j = idx & 7, lane = (idx >> 3) & 63, ks = (idx >> 9) & 7,
        gg = (idx >> 12) & 3, wv = (idx >> 14) & 15, d = (idx >> 18) & 1;
    int row = gg * 256 + wv * 16 + (lane & 15);
    int k = ks * 32 + ((lane >> 4) & 3) * 8 + j;
    wfrag0[idx] = f2bf(whh0[(d * 1024 + row) * 256 + k]);
    wfrag1[idx] = f2bf(whh1[(d * 1024 + row) * 256 + k]);
  }
  for (int idx = tid; idx < 2 * 1024; idx += nth) {
    bias0[idx] = bih0[idx] + bhh0[idx];
    bias1[idx] = bih1[idx] + bhh1[idx];
  }
}

// ---------------- MFMA input-projection GEMM -> gate-packed gx2[dir][m][unit][gate] ----------------
// Block: 256 thr, grid (Mn/64, 2). A (64 x K bf16) staged in LDS once; 16 n-tiles, no inner barriers.
template <int KS, bool GATHER>   // KS = K/32
__global__ __launch_bounds__(256) void gemm_ih(
    const void* __restrict__ xsrc_v,   // GATHER: fp32 emb; else bf16 rows [M][512]
    const int* __restrict__ sent,
    const uint4* __restrict__ wifrag,  // [2][16][4][KS][64] uint4
    const float* __restrict__ bias,    // [2][1024]
    u16* __restrict__ gx2)             // [2*M][256][4] bf16
{
  constexpr int K = KS * 32;
  constexpr int PITCH = K + 8;        // u16; K=256->264 (528B, 16B-mult), K=512->520 (1040B, 16B-mult)
  __shared__ u16 As[64][PITCH];
  const int tid = threadIdx.x;
  const int l = tid & 63;
  const int w = tid >> 6;
  const int col = l & 15;
  const int quad = (l >> 4) & 3;
  const int m0 = blockIdx.x * 64;
  const int dir = blockIdx.y;

  // stage A: row lr = tid>>2, quarter lq = tid&3
  {
    const int lr = tid >> 2, lq = tid & 3;
    if constexpr (GATHER) {
      const float4* xrow = reinterpret_cast<const float4*>(
          (const float*)xsrc_v + (size_t)sent[m0 + lr] * 256) + lq * 16;
      u32* dst = reinterpret_cast<u32*>(&As[lr][lq * 64]);
#pragma unroll
      for (int i = 0; i < 16; ++i) {
        float4 v = xrow[i];
        dst[i * 2 + 0] = (u32)f2bf(v.x) | ((u32)f2bf(v.y) << 16);
        dst[i * 2 + 1] = (u32)f2bf(v.z) | ((u32)f2bf(v.w) << 16);
      }
    } else {
      const uint4* xrow = reinterpret_cast<const uint4*>(
          (const u16*)xsrc_v + (size_t)(m0 + lr) * 512) + lq * 16;
      uint4* dst = reinterpret_cast<uint4*>(&As[lr][lq * 128]);
#pragma unroll
      for (int i = 0; i < 16; ++i) dst[i] = xrow[i];
    }
  }
  __syncthreads();

  const uint4* wfd = wifrag + (size_t)dir * 16 * 4 * KS * 64;
#pragma unroll 1
  for (int nb = 0; nb < 16; ++nb) {
    uint4 bf[KS];
#pragma unroll
    for (int ks = 0; ks < KS; ++ks)
      bf[ks] = wfd[((nb * 4 + w) * KS + ks) * 64 + l];

    f32x4 acc[4];
#pragma unroll
    for (int mt = 0; mt < 4; ++mt) acc[mt] = (f32x4){0.f, 0.f, 0.f, 0.f};
#pragma unroll
    for (int ks = 0; ks < KS; ++ks) {
      short8 b8 = __builtin_bit_cast(short8, bf[ks]);
#pragma unroll
      for (int mt = 0; mt < 4; ++mt) {
        uint4 av = *reinterpret_cast<const uint4*>(&As[mt * 16 + col][ks * 32 + quad * 8]);
        acc[mt] = __builtin_amdgcn_mfma_f32_16x16x32_bf16(
            __builtin_bit_cast(short8, av), b8, acc[mt], 0, 0, 0);
      }
    }

    const int n = nb * 64 + w * 16 + col;
    const int gate = n >> 8, unit = n & 255;
    const float bv = bias[dir * 1024 + n];
#pragma unroll
    for (int mt = 0; mt < 4; ++mt) {
#pragma unroll
      for (int r = 0; r < 4; ++r) {
        int m = m0 + mt * 16 + quad * 4 + r;
        gx2[((size_t)(dir * Mn + m) * 256 + unit) * 4 + gate] = f2bf(acc[mt][r] + bv);
      }
    }
  }
}

// ---------------- MFMA recurrence v7: self-contained block, weights in VGPRs --------------
// Grid: 8 blocks = (dir 2) x (batch-group 4). Block: 1024 thr = 16 waves.
// Wave w owns units [w*16, w*16+16) x 4 gates; B-frags (128 VGPR/lane) held in registers.
// Per step: ds_read A(h) frags -> 32 MFMA -> nonlin -> ds_write h -> ONE barrier.
__global__ __launch_bounds__(1024, 4) void lstm_recur_v7(
    const uint4* __restrict__ wfragR,  // [2][16][4][8][64] uint4
    const u16* __restrict__ gx2,       // [2*Mn][256][4] bf16
    u16* __restrict__ out)             // [B][S][512] bf16
{
  __shared__ u16 Ah[2][16][264];       // double-buffered h tile [16 rows][256 units]
  const int tid = threadIdx.x;
  const int l = tid & 63;
  const int w = tid >> 6;              // wave 0..15
  const int col = l & 15;
  const int quad = (l >> 4) & 3;
  const int m0 = quad * 4;
  const int dir = blockIdx.x >> 2;
  const int bg = blockIdx.x & 3;
  const int unit = w * 16 + col;

  // ---- load recurrent weights into registers: 32 x dwordx4 per lane ----
  uint4 bw[4][8];
#pragma unroll
  for (int g = 0; g < 4; ++g)
#pragma unroll
    for (int ks = 0; ks < 8; ++ks)
      bw[g][ks] = wfragR[((((size_t)dir * 16 + w) * 4 + g) * 8 + ks) * 64 + l];

  // ---- per-r global pointers ----
  const uint2* gpr[4];
  u16* opr[4];
#pragma unroll
  for (int r = 0; r < 4; ++r) {
    const int mrow = bg * 16 + m0 + r;
    gpr[r] = reinterpret_cast<const uint2*>(gx2) +
             (size_t)(dir * Mn + mrow * Sn) * 256 + unit;
    opr[r] = out + (size_t)mrow * Sn * HIDn + dir * Hn + unit;
  }

  float c[4] = {0.f, 0.f, 0.f, 0.f};
  uint2 gxv[4];

  // ---- s = 0: h_prev = 0, gates = gx only ----
  {
    const int t0 = dir ? (Sn - 1) : 0;
#pragma unroll
    for (int r = 0; r < 4; ++r) gxv[r] = gpr[r][(size_t)t0 * 256];
#pragma unroll
    for (int r = 0; r < 4; ++r) {
      float gi_ = b2f((u16)(gxv[r].x & 0xffff));
      float gg_ = b2f((u16)(gxv[r].y & 0xffff));
      float go_ = b2f((u16)(gxv[r].y >> 16));
      c[r] = sigf(gi_) * tanh_f(gg_);
      u16 hb = f2bf(sigf(go_) * tanh_f(c[r]));
      Ah[1][m0 + r][unit] = hb;
      opr[r][(size_t)t0 * HIDn] = hb;
    }
    const int t1 = dir ? (Sn - 2) : 1;
#pragma unroll
    for (int r = 0; r < 4; ++r) gxv[r] = gpr[r][(size_t)t1 * 256];
    __syncthreads();
  }

  // ---- main loop: one barrier per step ----
  for (int s = 1; s < Sn; ++s) {
    const int t = dir ? (Sn - 1 - s) : s;
    const int tn = dir ? (s >= Sn - 1 ? 0 : Sn - 2 - s)
                       : (s >= Sn - 1 ? Sn - 1 : s + 1);
    const int rb = s & 1;
    const int wb = rb ^ 1;

    // prefetch next step's gx (consumed next iteration)
    uint2 gn[4];
#pragma unroll
    for (int r = 0; r < 4; ++r) gn[r] = gpr[r][(size_t)tn * 256];

    // A-fragments of h(s-1) from LDS
    uint4 av[8];
#pragma unroll
    for (int ks = 0; ks < 8; ++ks)
      av[ks] = *reinterpret_cast<const uint4*>(&Ah[rb][col][ks * 32 + quad * 8]);

    f32x4 acc[4];
#pragma unroll
    for (int g = 0; g < 4; ++g) acc[g] = (f32x4){0.f, 0.f, 0.f, 0.f};
#pragma unroll
    for (int ks = 0; ks < 8; ++ks) {
      short8 a8 = __builtin_bit_cast(short8, av[ks]);
#pragma unroll
      for (int g = 0; g < 4; ++g)
        acc[g] = __builtin_amdgcn_mfma_f32_16x16x32_bf16(
            a8, __builtin_bit_cast(short8, bw[g][ks]), acc[g], 0, 0, 0);
    }

    u16 hbf[4];
#pragma unroll
    for (int r = 0; r < 4; ++r) {
      float gi_ = acc[0][r] + b2f((u16)(gxv[r].x & 0xffff));
      float gf_ = acc[1][r] + b2f((u16)(gxv[r].x >> 16));
      float gg_ = acc[2][r] + b2f((u16)(gxv[r].y & 0xffff));
      float go_ = acc[3][r] + b2f((u16)(gxv[r].y >> 16));
      c[r] = sigf(gf_) * c[r] + sigf(gi_) * tanh_f(gg_);
      hbf[r] = f2bf(sigf(go_) * tanh_f(c[r]));
    }
#pragma unroll
    for (int r = 0; r < 4; ++r) {
      Ah[wb][m0 + r][unit] = hbf[r];
      opr[r][(size_t)t * HIDn] = hbf[r];
    }
#pragma unroll
    for (int r = 0; r < 4; ++r) gxv[r] = gn[r];
    __syncthreads();
  }
}

// ---------------- FC: one wave per (b,t), bf16 input rows ----------------
__global__ __launch_bounds__(64) void fc_kernel(const u16* __restrict__ out1,
                                                const float* __restrict__ fcw,
                                                const float* __restrict__ fcb,
                                                float* __restrict__ feats) {
  const int bs = blockIdx.x;
  const int l = threadIdx.x;
  const u16* row = out1 + (size_t)bs * HIDn;
  uint4 rv = *reinterpret_cast<const uint4*>(row + l * 8);
  float v[8];
  v[0] = bflo(rv.x); v[1] = bfhi(rv.x);
  v[2] = bflo(rv.y); v[3] = bfhi(rv.y);
  v[4] = bflo(rv.z); v[5] = bfhi(rv.z);
  v[6] = bflo(rv.w); v[7] = bfhi(rv.w);
#pragma unroll
  for (int tag = 0; tag < Tn; ++tag) {
    const float* w = fcw + tag * HIDn + l * 8;
    float4 w0 = *reinterpret_cast<const float4*>(w);
    float4 w1 = *reinterpret_cast<const float4*>(w + 4);
    float acc = v[0] * w0.x + v[1] * w0.y + v[2] * w0.z + v[3] * w0.w
              + v[4] * w1.x + v[5] * w1.y + v[6] * w1.z + v[7] * w1.w;
#pragma unroll
    for (int off = 32; off; off >>= 1) acc += __shfl_xor(acc, off);
    if (l == 0) feats[bs * Tn + tag] = acc + fcb[tag];
  }
}

// ---------------- CRF forward + gold, one wave per batch ----------------
__global__ __launch_bounds__(64) void crf_kernel(const float* __restrict__ feats,
                                                 const int* __restrict__ tags,
                                                 const int* __restrict__ lens,
                                                 const float* __restrict__ trans,
                                                 float* __restrict__ scores) {
  const int b = blockIdx.x;
  const int j = threadIdx.x;
  const int jj = j < Tn ? j : Tn - 1;
  const int len = lens[b];

  float trc[Tn];
#pragma unroll
  for (int i = 0; i < Tn; ++i) trc[i] = trans[i * Tn + jj];
  const float trS = trans[jj * Tn + STOP_T];

  float alpha = (j == START_T) ? 0.0f : NEGV;
  const float* fb = feats + (size_t)b * Sn * Tn;

  for (int t = 0; t < Sn; ++t) {
    float f = (j < Tn) ? fb[t * Tn + j] : 0.0f;
    float v[Tn];
    float m = -3.0e38f;
#pragma unroll
    for (int i = 0; i < Tn; ++i) {
      float ai = __shfl(alpha, i);
      v[i] = ai + trc[i];
      m = fmaxf(m, v[i]);
    }
    float ssum = 0.0f;
#pragma unroll
    for (int i = 0; i < Tn; ++i) ssum += __expf(v[i] - m);
    float newa = m + __logf(ssum) + f;
    if (t < len && j < Tn) alpha = newa;
  }

  float val = (j < Tn) ? alpha + trS : -3.0e38f;
  float m = val;
#pragma unroll
  for (int off = 32; off; off >>= 1) m = fmaxf(m, __shfl_xor(m, off));
  float se = (j < Tn) ? __expf(val - m) : 0.0f;
#pragma unroll
  for (int off = 32; off; off >>= 1) se += __shfl_xor(se, off);
  float fscore = m + __logf(se);

  const int* tg = tags + b * Sn;
  float part = 0.0f;
  for (int q = 0; q < 8; ++q) {
    int s0 = j * 8 + q;
    if (s0 < Sn - 1 && (s0 + 1) < len) {
      int ta = tg[s0], tb = tg[s0 + 1];
      part += trans[ta * Tn + tb] + fb[s0 * Tn + tb];
    }
  }
#pragma unroll
  for (int off = 32; off; off >>= 1) part += __shfl_xor(part, off);

  if (j == 0) {
    int t0 = tg[0];
    int tl = tg[len - 1];
    float gold = trans[START_T * Tn + t0] + fb[0 * Tn + t0] + part + trans[tl * Tn + STOP_T];
    scores[b] = fscore - gold;
  }
}

__global__ void finalize_kernel(const float* __restrict__ scores, float* __restrict__ out) {
  int l = threadIdx.x;
  float v = scores[l];
#pragma unroll
  for (int off = 32; off; off >>= 1) v += __shfl_xor(v, off);
  if (l == 0) out[0] = v / 64.0f;
}

extern "C" void kernel_launch(void* const* d_in, const int* in_sizes, int n_in,
                              void* d_out, int out_size, void* d_ws, size_t ws_size,
                              hipStream_t stream) {
  const int* sent = (const int*)d_in[0];
  const int* tags = (const int*)d_in[1];
  const int* lens = (const int*)d_in[2];
  const float* emb = (const float*)d_in[3];
  const float* wih0 = (const float*)d_in[4];
  const float* whh0 = (const float*)d_in[5];
  const float* bih0 = (const float*)d_in[6];
  const float* bhh0 = (const float*)d_in[7];
  const float* wih1 = (const float*)d_in[8];
  const float* whh1 = (const float*)d_in[9];
  const float* bih1 = (const float*)d_in[10];
  const float* bhh1 = (const float*)d_in[11];
  const float* fcw = (const float*)d_in[12];
  const float* fcb = (const float*)d_in[13];
  const float* trans = (const float*)d_in[14];

  // workspace (~206 MB)
  char* ws = (char*)d_ws;
  u16* outb = (u16*)ws;                                  // 33,554,432 B
  u16* gx2 = (u16*)(ws + 33554432);                      // 134,217,728 B
  float* feats = (float*)gx2;                            // aliases gx2 (dead before fc)
  char* p = ws + 33554432 + 134217728;
  p += 33554432;                                         // (former hx region, unused)
  float* scores = (float*)p;            p += 256;
  float* bias0 = (float*)p;             p += 8192;
  float* bias1 = (float*)p;             p += 8192;
  u16* wifrag0 = (u16*)p;               p += 1048576;    // 524,288 u16
  u16* wifrag1 = (u16*)p;               p += 2097152;    // 1,048,576 u16
  u16* wfrag0 = (u16*)p;                p += 1048576;
  u16* wfrag1 = (u16*)p;                p += 1048576;

  prep_kernel<<<2048, 256, 0, stream>>>(wih0, whh0, bih0, bhh0, wih1, whh1, bih1, bhh1,
                                        wifrag0, wifrag1, wfrag0, wfrag1, bias0, bias1);

  dim3 ggrid(Mn / 64, 2);
  gemm_ih<8, true><<<ggrid, 256, 0, stream>>>(emb, sent, (const uint4*)wifrag0, bias0, gx2);
  lstm_recur_v7<<<8, 1024, 0, stream>>>((const uint4*)wfrag0, gx2, outb);
  gemm_ih<16, false><<<ggrid, 256, 0, stream>>>(outb, nullptr, (const uint4*)wifrag1, bias1, gx2);
  lstm_recur_v7<<<8, 1024, 0, stream>>>((const uint4*)wfrag1, gx2, outb);

  fc_kernel<<<Mn, 64, 0, stream>>>(outb, fcw, fcb, feats);
  crf_kernel<<<Bn, 64, 0, stream>>>(feats, tags, lens, trans, scores);
  finalize_kernel<<<1, 64, 0, stream>>>(scores, (float*)d_out);
}

// Round 3
// 3178.815 us; speedup vs baseline: 2.9463x; 2.9463x over previous
//
#include <hip/hip_runtime.h>
#include <math.h>

#define NEGV (-100000.0f)
constexpr int Bn = 64, Sn = 512, En = 256, Hn = 256, HIDn = 512, Tn = 9;
constexpr int START_T = Tn - 2, STOP_T = Tn - 1;
constexpr int Mn = Bn * Sn; // 32768 rows

typedef unsigned int u32;
typedef unsigned short u16;
typedef unsigned long long u64;
typedef short short8 __attribute__((ext_vector_type(8)));
typedef float f32x4 __attribute__((ext_vector_type(4)));

__device__ __forceinline__ float sigf(float x) { return 1.0f / (1.0f + __expf(-x)); }
__device__ __forceinline__ float tanh_f(float x) { return 2.0f / (1.0f + __expf(-2.0f * x)) - 1.0f; }
__device__ __forceinline__ u16 f2bf(float f) {
  u32 u = __float_as_uint(f);
  return (u16)((u + 0x7fffu + ((u >> 16) & 1u)) >> 16);
}
__device__ __forceinline__ float bflo(u32 u) { return __uint_as_float(u << 16); }
__device__ __forceinline__ float bfhi(u32 u) { return __uint_as_float(u & 0xffff0000u); }
__device__ __forceinline__ float b2f(u16 v) { return __uint_as_float((u32)v << 16); }

// ---------------- prep: all weights to bf16 MFMA B-fragment order ----------------
// whh frags (recur v8): wfragR[d][half][w(8)][g(4)][ks(8)][lane][j];
//   unit = half*128 + w*16 + (lane&15); row = g*256 + unit; k = ks*32+((lane>>4)&3)*8+j
// wih frags (gemm):     wifrag[d][nb][w][ks][lane][j]; n=nb*64+w*16+(lane&15); k=ks*32+((lane>>4)&3)*8+j
__global__ void prep_kernel(const float* __restrict__ wih0, const float* __restrict__ whh0,
                            const float* __restrict__ bih0, const float* __restrict__ bhh0,
                            const float* __restrict__ wih1, const float* __restrict__ whh1,
                            const float* __restrict__ bih1, const float* __restrict__ bhh1,
                            u16* __restrict__ wifrag0, u16* __restrict__ wifrag1,
                            u16* __restrict__ wfrag0, u16* __restrict__ wfrag1,
                            float* __restrict__ bias0, float* __restrict__ bias1) {
  int tid = blockIdx.x * blockDim.x + threadIdx.x;
  int nth = gridDim.x * blockDim.x;
  // wih0 frags: K=256, KS=8 -> 2*16*4*8*64*8 = 524288 u16
  for (int idx = tid; idx < 524288; idx += nth) {
    int j = idx & 7, lane = (idx >> 3) & 63, ks = (idx >> 9) & 7,
        w2 = (idx >> 12) & 3, nb = (idx >> 14) & 15, d = (idx >> 18) & 1;
    int n = nb * 64 + w2 * 16 + (lane & 15);
    int k = ks * 32 + ((lane >> 4) & 3) * 8 + j;
    wifrag0[idx] = f2bf(wih0[(d * 1024 + n) * 256 + k]);
  }
  // wih1 frags: K=512, KS=16 -> 2*16*4*16*64*8 = 1048576 u16
  for (int idx = tid; idx < 1048576; idx += nth) {
    int j = idx & 7, lane = (idx >> 3) & 63, ks = (idx >> 9) & 15,
        w2 = (idx >> 13) & 3, nb = (idx >> 15) & 15, d = (idx >> 19) & 1;
    int n = nb * 64 + w2 * 16 + (lane & 15);
    int k = ks * 32 + ((lane >> 4) & 3) * 8 + j;
    wifrag1[idx] = f2bf(wih1[(d * 1024 + n) * 512 + k]);
  }
  // whh frags, v8 layout: [d][half][w][g][ks][lane][j]
  for (int idx = tid; idx < 524288; idx += nth) {
    int j = idx & 7, lane = (idx >> 3) & 63, ks = (idx >> 9) & 7,
        gg = (idx >> 12) & 3, wv = (idx >> 14) & 7, hf = (idx >> 17) & 1,
        d = (idx >> 18) & 1;
    int unit = hf * 128 + wv * 16 + (lane & 15);
    int row = gg * 256 + unit;
    int k = ks * 32 + ((lane >> 4) & 3) * 8 + j;
    wfrag0[idx] = f2bf(whh0[(d * 1024 + row) * 256 + k]);
    wfrag1[idx] = f2bf(whh1[(d * 1024 + row) * 256 + k]);
  }
  for (int idx = tid; idx < 2 * 1024; idx += nth) {
    bias0[idx] = bih0[idx] + bhh0[idx];
    bias1[idx] = bih1[idx] + bhh1[idx];
  }
}

// ---------------- MFMA input-projection GEMM -> gate-packed gx2[dir][m][unit][gate] ----------------
// Block: 256 thr, grid (Mn/64, 2). A (64 x K bf16) staged in LDS once; 16 n-tiles, no inner barriers.
template <int KS, bool GATHER>   // KS = K/32
__global__ __launch_bounds__(256) void gemm_ih(
    const void* __restrict__ xsrc_v,   // GATHER: fp32 emb; else bf16 rows [M][512]
    const int* __restrict__ sent,
    const uint4* __restrict__ wifrag,  // [2][16][4][KS][64] uint4
    const float* __restrict__ bias,    // [2][1024]
    u16* __restrict__ gx2)             // [2*M][256][4] bf16
{
  constexpr int K = KS * 32;
  constexpr int PITCH = K + 8;        // u16; K=256->264 (528B, 16B-mult), K=512->520 (1040B, 16B-mult)
  __shared__ u16 As[64][PITCH];
  const int tid = threadIdx.x;
  const int l = tid & 63;
  const int w = tid >> 6;
  const int col = l & 15;
  const int quad = (l >> 4) & 3;
  const int m0 = blockIdx.x * 64;
  const int dir = blockIdx.y;

  // stage A: row lr = tid>>2, quarter lq = tid&3
  {
    const int lr = tid >> 2, lq = tid & 3;
    if constexpr (GATHER) {
      const float4* xrow = reinterpret_cast<const float4*>(
          (const float*)xsrc_v + (size_t)sent[m0 + lr] * 256) + lq * 16;
      u32* dst = reinterpret_cast<u32*>(&As[lr][lq * 64]);
#pragma unroll
      for (int i = 0; i < 16; ++i) {
        float4 v = xrow[i];
        dst[i * 2 + 0] = (u32)f2bf(v.x) | ((u32)f2bf(v.y) << 16);
        dst[i * 2 + 1] = (u32)f2bf(v.z) | ((u32)f2bf(v.w) << 16);
      }
    } else {
      const uint4* xrow = reinterpret_cast<const uint4*>(
          (const u16*)xsrc_v + (size_t)(m0 + lr) * 512) + lq * 16;
      uint4* dst = reinterpret_cast<uint4*>(&As[lr][lq * 128]);
#pragma unroll
      for (int i = 0; i < 16; ++i) dst[i] = xrow[i];
    }
  }
  __syncthreads();

  const uint4* wfd = wifrag + (size_t)dir * 16 * 4 * KS * 64;
#pragma unroll 1
  for (int nb = 0; nb < 16; ++nb) {
    uint4 bf[KS];
#pragma unroll
    for (int ks = 0; ks < KS; ++ks)
      bf[ks] = wfd[((nb * 4 + w) * KS + ks) * 64 + l];

    f32x4 acc[4];
#pragma unroll
    for (int mt = 0; mt < 4; ++mt) acc[mt] = (f32x4){0.f, 0.f, 0.f, 0.f};
#pragma unroll
    for (int ks = 0; ks < KS; ++ks) {
      short8 b8 = __builtin_bit_cast(short8, bf[ks]);
#pragma unroll
      for (int mt = 0; mt < 4; ++mt) {
        uint4 av = *reinterpret_cast<const uint4*>(&As[mt * 16 + col][ks * 32 + quad * 8]);
        acc[mt] = __builtin_amdgcn_mfma_f32_16x16x32_bf16(
            __builtin_bit_cast(short8, av), b8, acc[mt], 0, 0, 0);
      }
    }

    const int n = nb * 64 + w * 16 + col;
    const int gate = n >> 8, unit = n & 255;
    const float bv = bias[dir * 1024 + n];
#pragma unroll
    for (int mt = 0; mt < 4; ++mt) {
#pragma unroll
      for (int r = 0; r < 4; ++r) {
        int m = m0 + mt * 16 + quad * 4 + r;
        gx2[((size_t)(dir * Mn + m) * 256 + unit) * 4 + gate] = f2bf(acc[mt][r] + bv);
      }
    }
  }
}

// ---------------- MFMA recurrence v8: 2-way unit split, weights in VGPRs --------------
// Grid: 16 blocks = (half 2) x (dir 2 x bg 4). Block: 512 thr = 8 waves, 2 waves/SIMD (cap 256 VGPR).
// Wave w owns units half*128 + w*16 + col, all 4 gates, full K=256: bw[4][8] = 128 VGPRs.
// Per step: spin 1 u64 (remote half h) -> scatter -> BAR -> ds_read A -> 32 MFMA -> nonlin
//           -> agent-store own u64 pack -> LDS/out writes. Triple-buffered Ah => 1 barrier/step.
__global__ __launch_bounds__(512, 2) void lstm_recur_v8(
    const uint4* __restrict__ wfragR,  // [2][2][8][4][8][64] uint4
    const u16* __restrict__ gx2,       // [2*Mn][256][4] bf16
    u64* __restrict__ hx,              // [8 g8][2 half][512 s][512 p] u64
    u16* __restrict__ out)             // [B][S][512] bf16
{
  __shared__ u16 Ah[3][16][264];       // triple-buffered h tile [16 rows][256 units]
  const int tid = threadIdx.x;
  const int l = tid & 63;
  const int w = tid >> 6;              // wave 0..7
  const int col = l & 15;
  const int quad = (l >> 4) & 3;
  const int m0 = quad * 4;
  const int half = blockIdx.x >> 3;
  const int g8 = blockIdx.x & 7;
  const int dir = g8 >> 2, bg = g8 & 3;
  const int ul = w * 16 + col;         // local unit index 0..127
  const int u = half * 128 + ul;       // global unit 0..255
  const int ur = (half ^ 1) * 128 + ul;// mirrored remote unit
  const int p = ul * 4 + quad;         // pack slot 0..511

  // ---- recurrent weights into registers: 32 x dwordx4 per lane (128 VGPR) ----
  uint4 bw[4][8];
  {
    const uint4* wf = wfragR + (((size_t)(dir * 2 + half) * 8 + w) * 32) * 64;
#pragma unroll
    for (int g = 0; g < 4; ++g)
#pragma unroll
      for (int ks = 0; ks < 8; ++ks)
        bw[g][ks] = wf[(g * 8 + ks) * 64 + l];
  }

  u64* mystore = hx + ((size_t)(g8 * 2 + half) * 512) * 512 + p;
  const u64* rload = hx + ((size_t)(g8 * 2 + (half ^ 1)) * 512) * 512 + p;

  // ---- per-r global pointers ----
  const uint2* gbase[4];
  u16* outp[4];
#pragma unroll
  for (int r = 0; r < 4; ++r) {
    const int mrow = bg * 16 + m0 + r;
    gbase[r] = reinterpret_cast<const uint2*>(gx2) +
               (size_t)(dir * Mn + mrow * Sn) * 256 + u;
    outp[r] = out + (size_t)mrow * Sn * HIDn + dir * Hn + u;
  }

  float c[4] = {0.f, 0.f, 0.f, 0.f};
  uint2 gxv[4];

  // ---- s = 0: h_prev = 0 ----
  {
    const int t0 = dir ? (Sn - 1) : 0;
#pragma unroll
    for (int r = 0; r < 4; ++r) gxv[r] = gbase[r][(size_t)t0 * 256];
    u16 hbf[4];
#pragma unroll
    for (int r = 0; r < 4; ++r) {
      float gi_ = b2f((u16)(gxv[r].x & 0xffff));
      float gg_ = b2f((u16)(gxv[r].y & 0xffff));
      float go_ = b2f((u16)(gxv[r].y >> 16));
      c[r] = sigf(gi_) * tanh_f(gg_);
      hbf[r] = f2bf(sigf(go_) * tanh_f(c[r]));
    }
    u64 hpack = (u64)hbf[0] | ((u64)hbf[1] << 16) | ((u64)hbf[2] << 32) | ((u64)hbf[3] << 48);
    __hip_atomic_store(mystore, hpack, __ATOMIC_RELAXED, __HIP_MEMORY_SCOPE_AGENT);
#pragma unroll
    for (int r = 0; r < 4; ++r) {
      Ah[1][m0 + r][u] = hbf[r];
      outp[r][(size_t)t0 * HIDn] = hbf[r];
    }
    const int t1 = dir ? (Sn - 2) : 1;
#pragma unroll
    for (int r = 0; r < 4; ++r) gxv[r] = gbase[r][(size_t)t1 * 256];
  }

  // ---- main loop: one barrier per step ----
  int bufR = 1;
  for (int s = 1; s < Sn; ++s) {
    const int t = dir ? (Sn - 1 - s) : s;
    const int tn = dir ? (s >= Sn - 1 ? 0 : Sn - 2 - s)
                       : (s >= Sn - 1 ? Sn - 1 : s + 1);
    const int bufW = (bufR == 2) ? 0 : bufR + 1;

    // spin for remote half's h(s-1): exactly one u64 per lane
    {
      const u64* rp = rload + (size_t)(s - 1) * 512;
      u64 v = __hip_atomic_load(rp, __ATOMIC_RELAXED, __HIP_MEMORY_SCOPE_AGENT);
      while (v == ~0ULL)
        v = __hip_atomic_load(rp, __ATOMIC_RELAXED, __HIP_MEMORY_SCOPE_AGENT);
#pragma unroll
      for (int r = 0; r < 4; ++r)
        Ah[bufR][m0 + r][ur] = (u16)(v >> (r * 16));
    }
    __syncthreads();

    // prefetch next step's gx early (hides HBM latency under MFMA)
    uint2 gn[4];
#pragma unroll
    for (int r = 0; r < 4; ++r) gn[r] = gbase[r][(size_t)tn * 256];

    // A-fragments of h(s-1): full K = 256 units
    uint4 av[8];
#pragma unroll
    for (int ks = 0; ks < 8; ++ks)
      av[ks] = *reinterpret_cast<const uint4*>(&Ah[bufR][col][ks * 32 + quad * 8]);

    f32x4 acc[4];
#pragma unroll
    for (int g = 0; g < 4; ++g) acc[g] = (f32x4){0.f, 0.f, 0.f, 0.f};
#pragma unroll
    for (int ks = 0; ks < 8; ++ks) {
      short8 a8 = __builtin_bit_cast(short8, av[ks]);
#pragma unroll
      for (int g = 0; g < 4; ++g)
        acc[g] = __builtin_amdgcn_mfma_f32_16x16x32_bf16(
            a8, __builtin_bit_cast(short8, bw[g][ks]), acc[g], 0, 0, 0);
    }

    u16 hbf[4];
#pragma unroll
    for (int r = 0; r < 4; ++r) {
      float gi_ = acc[0][r] + b2f((u16)(gxv[r].x & 0xffff));
      float gf_ = acc[1][r] + b2f((u16)(gxv[r].x >> 16));
      float gg_ = acc[2][r] + b2f((u16)(gxv[r].y & 0xffff));
      float go_ = acc[3][r] + b2f((u16)(gxv[r].y >> 16));
      c[r] = sigf(gf_) * c[r] + sigf(gi_) * tanh_f(gg_);
      hbf[r] = f2bf(sigf(go_) * tanh_f(c[r]));
    }
    // cross-block store FIRST (partner's critical path)
    u64 hpack = (u64)hbf[0] | ((u64)hbf[1] << 16) | ((u64)hbf[2] << 32) | ((u64)hbf[3] << 48);
    __hip_atomic_store(mystore + (size_t)s * 512, hpack,
                       __ATOMIC_RELAXED, __HIP_MEMORY_SCOPE_AGENT);
#pragma unroll
    for (int r = 0; r < 4; ++r) {
      Ah[bufW][m0 + r][u] = hbf[r];
      outp[r][(size_t)t * HIDn] = hbf[r];
    }
#pragma unroll
    for (int r = 0; r < 4; ++r) gxv[r] = gn[r];
    bufR = bufW;
  }
}

// ---------------- FC: one wave per (b,t), bf16 input rows ----------------
__global__ __launch_bounds__(64) void fc_kernel(const u16* __restrict__ out1,
                                                const float* __restrict__ fcw,
                                                const float* __restrict__ fcb,
                                                float* __restrict__ feats) {
  const int bs = blockIdx.x;
  const int l = threadIdx.x;
  const u16* row = out1 + (size_t)bs * HIDn;
  uint4 rv = *reinterpret_cast<const uint4*>(row + l * 8);
  float v[8];
  v[0] = bflo(rv.x); v[1] = bfhi(rv.x);
  v[2] = bflo(rv.y); v[3] = bfhi(rv.y);
  v[4] = bflo(rv.z); v[5] = bfhi(rv.z);
  v[6] = bflo(rv.w); v[7] = bfhi(rv.w);
#pragma unroll
  for (int tag = 0; tag < Tn; ++tag) {
    const float* w = fcw + tag * HIDn + l * 8;
    float4 w0 = *reinterpret_cast<const float4*>(w);
    float4 w1 = *reinterpret_cast<const float4*>(w + 4);
    float acc = v[0] * w0.x + v[1] * w0.y + v[2] * w0.z + v[3] * w0.w
              + v[4] * w1.x + v[5] * w1.y + v[6] * w1.z + v[7] * w1.w;
#pragma unroll
    for (int off = 32; off; off >>= 1) acc += __shfl_xor(acc, off);
    if (l == 0) feats[bs * Tn + tag] = acc + fcb[tag];
  }
}

// ---------------- CRF forward + gold, one wave per batch ----------------
__global__ __launch_bounds__(64) void crf_kernel(const float* __restrict__ feats,
                                                 const int* __restrict__ tags,
                                                 const int* __restrict__ lens,
                                                 const float* __restrict__ trans,
                                                 float* __restrict__ scores) {
  const int b = blockIdx.x;
  const int j = threadIdx.x;
  const int jj = j < Tn ? j : Tn - 1;
  const int len = lens[b];

  float trc[Tn];
#pragma unroll
  for (int i = 0; i < Tn; ++i) trc[i] = trans[i * Tn + jj];
  const float trS = trans[jj * Tn + STOP_T];

  float alpha = (j == START_T) ? 0.0f : NEGV;
  const float* fb = feats + (size_t)b * Sn * Tn;

  for (int t = 0; t < Sn; ++t) {
    float f = (j < Tn) ? fb[t * Tn + j] : 0.0f;
    float v[Tn];
    float m = -3.0e38f;
#pragma unroll
    for (int i = 0; i < Tn; ++i) {
      float ai = __shfl(alpha, i);
      v[i] = ai + trc[i];
      m = fmaxf(m, v[i]);
    }
    float ssum = 0.0f;
#pragma unroll
    for (int i = 0; i < Tn; ++i) ssum += __expf(v[i] - m);
    float newa = m + __logf(ssum) + f;
    if (t < len && j < Tn) alpha = newa;
  }

  float val = (j < Tn) ? alpha + trS : -3.0e38f;
  float m = val;
#pragma unroll
  for (int off = 32; off; off >>= 1) m = fmaxf(m, __shfl_xor(m, off));
  float se = (j < Tn) ? __expf(val - m) : 0.0f;
#pragma unroll
  for (int off = 32; off; off >>= 1) se += __shfl_xor(se, off);
  float fscore = m + __logf(se);

  const int* tg = tags + b * Sn;
  float part = 0.0f;
  for (int q = 0; q < 8; ++q) {
    int s0 = j * 8 + q;
    if (s0 < Sn - 1 && (s0 + 1) < len) {
      int ta = tg[s0], tb = tg[s0 + 1];
      part += trans[ta * Tn + tb] + fb[s0 * Tn + tb];
    }
  }
#pragma unroll
  for (int off = 32; off; off >>= 1) part += __shfl_xor(part, off);

  if (j == 0) {
    int t0 = tg[0];
    int tl = tg[len - 1];
    float gold = trans[START_T * Tn + t0] + fb[0 * Tn + t0] + part + trans[tl * Tn + STOP_T];
    scores[b] = fscore - gold;
  }
}

__global__ void finalize_kernel(const float* __restrict__ scores, float* __restrict__ out) {
  int l = threadIdx.x;
  float v = scores[l];
#pragma unroll
  for (int off = 32; off; off >>= 1) v += __shfl_xor(v, off);
  if (l == 0) out[0] = v / 64.0f;
}

extern "C" void kernel_launch(void* const* d_in, const int* in_sizes, int n_in,
                              void* d_out, int out_size, void* d_ws, size_t ws_size,
                              hipStream_t stream) {
  const int* sent = (const int*)d_in[0];
  const int* tags = (const int*)d_in[1];
  const int* lens = (const int*)d_in[2];
  const float* emb = (const float*)d_in[3];
  const float* wih0 = (const float*)d_in[4];
  const float* whh0 = (const float*)d_in[5];
  const float* bih0 = (const float*)d_in[6];
  const float* bhh0 = (const float*)d_in[7];
  const float* wih1 = (const float*)d_in[8];
  const float* whh1 = (const float*)d_in[9];
  const float* bih1 = (const float*)d_in[10];
  const float* bhh1 = (const float*)d_in[11];
  const float* fcw = (const float*)d_in[12];
  const float* fcb = (const float*)d_in[13];
  const float* trans = (const float*)d_in[14];

  // workspace (~206 MB)
  char* ws = (char*)d_ws;
  u16* outb = (u16*)ws;                                  // 33,554,432 B
  u16* gx2 = (u16*)(ws + 33554432);                      // 134,217,728 B
  float* feats = (float*)gx2;                            // aliases gx2 (dead before fc)
  char* p = ws + 33554432 + 134217728;
  u64* hx = (u64*)p;                    p += 33554432;   // [8][2][512][512] u64
  float* scores = (float*)p;            p += 256;
  float* bias0 = (float*)p;             p += 8192;
  float* bias1 = (float*)p;             p += 8192;
  u16* wifrag0 = (u16*)p;               p += 1048576;    // 524,288 u16
  u16* wifrag1 = (u16*)p;               p += 2097152;    // 1,048,576 u16
  u16* wfrag0 = (u16*)p;                p += 1048576;
  u16* wfrag1 = (u16*)p;                p += 1048576;

  prep_kernel<<<2048, 256, 0, stream>>>(wih0, whh0, bih0, bhh0, wih1, whh1, bih1, bhh1,
                                        wifrag0, wifrag1, wfrag0, wfrag1, bias0, bias1);

  dim3 ggrid(Mn / 64, 2);
  hipMemsetAsync(hx, 0xFF, 33554432, stream);
  gemm_ih<8, true><<<ggrid, 256, 0, stream>>>(emb, sent, (const uint4*)wifrag0, bias0, gx2);
  lstm_recur_v8<<<16, 512, 0, stream>>>((const uint4*)wfrag0, gx2, hx, outb);
  hipMemsetAsync(hx, 0xFF, 33554432, stream);
  gemm_ih<16, false><<<ggrid, 256, 0, stream>>>(outb, nullptr, (const uint4*)wifrag1, bias1, gx2);
  lstm_recur_v8<<<16, 512, 0, stream>>>((const uint4*)wfrag1, gx2, hx, outb);

  fc_kernel<<<Mn, 64, 0, stream>>>(outb, fcw, fcb, feats);
  crf_kernel<<<Bn, 64, 0, stream>>>(feats, tags, lens, trans, scores);
  finalize_kernel<<<1, 64, 0, stream>>>(scores, (float*)d_out);
}